// Round 2
// 495.334 us; speedup vs baseline: 1.1891x; 1.1891x over previous
//
#include <hip/hip_runtime.h>

typedef unsigned int u32;
typedef unsigned short u16;
typedef short s16x8 __attribute__((ext_vector_type(8)));
typedef float f32x4 __attribute__((ext_vector_type(4)));

#define SENT 0xFFFFFFFFu

// ---------- helpers ----------
__device__ __forceinline__ u16 f2bf(float f) {
  u32 u = __float_as_uint(f);
  u32 r = (u + 0x7fffu + ((u >> 16) & 1u)) >> 16;  // RNE
  return (u16)r;
}

// L1/L2-bypassing 16B load (same cache path as agent-scope atomics)
__device__ __forceinline__ uint4 load_u4_bypass(const u32* p) {
  uint4 r;
  asm volatile("global_load_dwordx4 %0, %1, off sc0 sc1\n\ts_waitcnt vmcnt(0)"
               : "=v"(r) : "v"(p) : "memory");
  return r;
}

// ---------- fp32 -> bf16 convert (vectorized) ----------
__global__ __launch_bounds__(256) void cvt_bf16_kernel(const float* __restrict__ src,
                                                       u16* __restrict__ dst, int n4) {
  int i = blockIdx.x * 256 + threadIdx.x;
  if (i >= n4) return;
  float4 v = reinterpret_cast<const float4*>(src)[i];
  u32 lo = (u32)f2bf(v.x) | ((u32)f2bf(v.y) << 16);
  u32 hi = (u32)f2bf(v.z) | ((u32)f2bf(v.w) << 16);
  reinterpret_cast<uint2*>(dst)[i] = make_uint2(lo, hi);
}

// ---------- build x = [emb[tok] ; thought] as bf16, rows m = s*16+b, K=1024 ----------
__global__ __launch_bounds__(128) void build_x_kernel(const int* __restrict__ tseq,
                                                      const float* __restrict__ emb,
                                                      const float* __restrict__ thought,
                                                      u16* __restrict__ x) {
  int m = blockIdx.x;  // 0..1023, m = s*16 + b
  int s = m >> 4, b = m & 15;
  int tid = threadIdx.x;  // 128
  int k = tid * 8;
  const float* src;
  if (k < 512) src = emb + (size_t)tseq[b * 64 + s] * 512 + k;
  else         src = thought + b * 512 + (k - 512);
  float4 v0 = reinterpret_cast<const float4*>(src)[0];
  float4 v1 = reinterpret_cast<const float4*>(src)[1];
  uint4 o;
  o.x = (u32)f2bf(v0.x) | ((u32)f2bf(v0.y) << 16);
  o.y = (u32)f2bf(v0.z) | ((u32)f2bf(v0.w) << 16);
  o.z = (u32)f2bf(v1.x) | ((u32)f2bf(v1.y) << 16);
  o.w = (u32)f2bf(v1.z) | ((u32)f2bf(v1.w) << 16);
  *reinterpret_cast<uint4*>(x + (size_t)m * 1024 + k) = o;
}

// ---------- bf16 MFMA GEMM: C[M,N] = A[M,K] * B[N,K]^T + bias, optional LSE partials ----------
template <bool LSE>
__global__ __launch_bounds__(256) void gemm_bt_kernel(const u16* __restrict__ A,
                                                      const u16* __restrict__ Bm,
                                                      const float* __restrict__ bias,
                                                      float* __restrict__ C,
                                                      int M_, int N_, int K_,
                                                      float* __restrict__ partials, int nnb) {
  __shared__ u16 sA[128 * 40];
  __shared__ u16 sB[128 * 40];
  __shared__ float pm[2][128];
  __shared__ float ps[2][128];
  int nb = blockIdx.x, mb = blockIdx.y;
  int m0 = mb * 128, n0 = nb * 128;
  int tid = threadIdx.x;
  int wave = tid >> 6, lane = tid & 63;
  int wm = wave >> 1, wn = wave & 1;
  int l16 = lane & 15, quad = lane >> 4;
  int srow = tid >> 1, shalf = tid & 1;
  const u16* gA = A + (size_t)(m0 + srow) * K_ + shalf * 16;
  const u16* gB = Bm + (size_t)(n0 + srow) * K_ + shalf * 16;
  u16* lA = &sA[srow * 40 + shalf * 16];
  u16* lB = &sB[srow * 40 + shalf * 16];
  f32x4 acc[4][4];
  for (int i = 0; i < 4; ++i)
    for (int j = 0; j < 4; ++j) acc[i][j] = (f32x4){0.f, 0.f, 0.f, 0.f};

  for (int k0 = 0; k0 < K_; k0 += 32) {
    uint4 a0 = *reinterpret_cast<const uint4*>(gA + k0);
    uint4 a1 = *reinterpret_cast<const uint4*>(gA + k0 + 8);
    uint4 b0 = *reinterpret_cast<const uint4*>(gB + k0);
    uint4 b1 = *reinterpret_cast<const uint4*>(gB + k0 + 8);
    __syncthreads();
    *reinterpret_cast<uint4*>(lA) = a0;
    *reinterpret_cast<uint4*>(lA + 8) = a1;
    *reinterpret_cast<uint4*>(lB) = b0;
    *reinterpret_cast<uint4*>(lB + 8) = b1;
    __syncthreads();
    s16x8 af[4], bfr[4];
    for (int mt = 0; mt < 4; ++mt)
      af[mt] = *reinterpret_cast<const s16x8*>(&sA[(wm * 64 + mt * 16 + l16) * 40 + quad * 8]);
    for (int nt = 0; nt < 4; ++nt)
      bfr[nt] = *reinterpret_cast<const s16x8*>(&sB[(wn * 64 + nt * 16 + l16) * 40 + quad * 8]);
    for (int mt = 0; mt < 4; ++mt)
      for (int nt = 0; nt < 4; ++nt)
        acc[mt][nt] = __builtin_amdgcn_mfma_f32_16x16x32_bf16(af[mt], bfr[nt], acc[mt][nt], 0, 0, 0);
  }

  int rbase = wm * 64 + quad * 4;
  int cbase = n0 + wn * 64 + l16;
  for (int nt = 0; nt < 4; ++nt) {
    float bv = bias[cbase + nt * 16];
    for (int mt = 0; mt < 4; ++mt)
      for (int r = 0; r < 4; ++r) acc[mt][nt][r] += bv;
  }
  for (int mt = 0; mt < 4; ++mt)
    for (int r = 0; r < 4; ++r) {
      int row = m0 + rbase + mt * 16 + r;
      for (int nt = 0; nt < 4; ++nt)
        C[(size_t)row * N_ + cbase + nt * 16] = acc[mt][nt][r];
    }
  if (LSE) {
    for (int mt = 0; mt < 4; ++mt)
      for (int r = 0; r < 4; ++r) {
        float mx = acc[mt][0][r];
        for (int nt = 1; nt < 4; ++nt) mx = fmaxf(mx, acc[mt][nt][r]);
        for (int d = 1; d < 16; d <<= 1) mx = fmaxf(mx, __shfl_xor(mx, d));
        float sm = 0.f;
        for (int nt = 0; nt < 4; ++nt) sm += __expf(acc[mt][nt][r] - mx);
        for (int d = 1; d < 16; d <<= 1) sm += __shfl_xor(sm, d);
        if (l16 == 0) {
          int rr = wm * 64 + mt * 16 + quad * 4 + r;
          pm[wn][rr] = mx;
          ps[wn][rr] = sm;
        }
      }
    __syncthreads();
    if (tid < 128) {
      float m1 = pm[0][tid], m2 = pm[1][tid];
      float s1 = ps[0][tid], s2 = ps[1][tid];
      float Mx = fmaxf(m1, m2);
      float Sx = s1 * __expf(m1 - Mx) + s2 * __expf(m2 - Mx);
      float* p = partials + ((size_t)(m0 + tid) * nnb + nb) * 2;
      p[0] = Mx;
      p[1] = Sx;
    }
  }
}

// ---------- GRU recurrence ----------
// 512 WGs = 16 batches x 32 row-slices; 256 threads.
// 16 row-groups (grp = tid>>4) of 16 lanes; group grp computes W_hh rows
// {grp, 16+grp, 32+grp} of its 48-row slice == exactly the r/z/n rows for
// output j = g*16+grp, so the gates are computed in-register right after the
// 16-lane shuffle reduce (no gh LDS round trip, one fewer barrier).
// Sync (PROVEN two-phase scheme, unchanged from the 589us baseline):
// phase 1: 32 lanes poll one flag word per writer slice; phase 2: 128 threads
// bulk-read 16B each via sc0|sc1 loads with sentinel re-validation (writers
// now span 4 waves -> occasional phase-2 retries, by design).
__global__ __launch_bounds__(256) void gru_kernel(const float* __restrict__ gi,
                                                  const float* __restrict__ W_hh,
                                                  const float* __restrict__ b_hh,
                                                  const float* __restrict__ hidden,
                                                  u32* __restrict__ hbase,  // [64][16][512]
                                                  u16* __restrict__ ys,     // [1024][512], m=b*64+t
                                                  float* __restrict__ hlast) {
  __shared__ u16 sW[48 * 520];   // padded stride 520
  __shared__ float h_s[576];     // padded: idx(j) = j + 4*(j>>5)
  int wg = blockIdx.x;
  int b = wg >> 5, g = wg & 31;
  int tid = threadIdx.x;  // 256

  // stage W slice (48 rows x 512) as bf16 into LDS
  for (int e = tid * 4; e < 48 * 512; e += 1024) {
    int lr = e >> 9, col = e & 511;
    int grow = (lr >> 4) * 512 + g * 16 + (lr & 15);
    float4 v = *reinterpret_cast<const float4*>(W_hh + (size_t)grow * 512 + col);
    u32 lo = (u32)f2bf(v.x) | ((u32)f2bf(v.y) << 16);
    u32 hi = (u32)f2bf(v.z) | ((u32)f2bf(v.w) << 16);
    *reinterpret_cast<uint2*>(&sW[lr * 520 + col]) = make_uint2(lo, hi);
  }
  int grp = tid >> 4, l16 = tid & 15;
  int j = g * 16 + grp;                  // output index for writer lane (l16==0)
  float bhr = 0.f, bhz = 0.f, bhn = 0.f;
  if (l16 == 0) { bhr = b_hh[j]; bhz = b_hh[512 + j]; bhn = b_hh[1024 + j]; }
  int j0 = tid * 4;                      // bulk-read base (16B per thread, tid<128)
  __syncthreads();

  for (int t = 0; t < 64; ++t) {
    // issue this step's gi loads early (independent of h_{t-1})
    float gir = 0.f, giz = 0.f, gin = 0.f;
    if (l16 == 0) {
      size_t gib = ((size_t)t * 16 + b) * 1536;
      gir = gi[gib + j]; giz = gi[gib + 512 + j]; gin = gi[gib + 1024 + j];
    }
    if (t > 0) {
      const u32* hp = hbase + (size_t)(t - 1) * 8192 + b * 512;
      // phase 1: 32 lanes poll one flag word per writer slice
      if (tid < 32) {
        const u32* fp = hp + tid * 16;
        u32 v = __hip_atomic_load(fp, __ATOMIC_RELAXED, __HIP_MEMORY_SCOPE_AGENT);
        while (v == SENT) {
          __builtin_amdgcn_s_sleep(2);
          v = __hip_atomic_load(fp, __ATOMIC_RELAXED, __HIP_MEMORY_SCOPE_AGENT);
        }
      }
      __syncthreads();
      // phase 2: bulk read 16B/thread, validate sentinels
      if (tid < 128) {
        uint4 v = load_u4_bypass(hp + j0);
        while (v.x == SENT || v.y == SENT || v.z == SENT || v.w == SENT) {
          __builtin_amdgcn_s_sleep(1);
          v = load_u4_bypass(hp + j0);
        }
        float4 f;
        f.x = __uint_as_float(v.x); f.y = __uint_as_float(v.y);
        f.z = __uint_as_float(v.z); f.w = __uint_as_float(v.w);
        *reinterpret_cast<float4*>(&h_s[j0 + ((j0 >> 5) << 2)]) = f;
      }
    } else {
      if (tid < 128) {
        float4 f = *reinterpret_cast<const float4*>(hidden + b * 512 + j0);
        *reinterpret_cast<float4*>(&h_s[j0 + ((j0 >> 5) << 2)]) = f;
      }
    }
    __syncthreads();
    // preload this lane's 32 h values (cols l16*32..+32)
    float hreg[32];
    int hb2 = l16 * 36;
    for (int c4 = 0; c4 < 4; ++c4) {
      float4 x0 = *reinterpret_cast<const float4*>(&h_s[hb2 + c4 * 8]);
      float4 x1 = *reinterpret_cast<const float4*>(&h_s[hb2 + c4 * 8 + 4]);
      hreg[c4 * 8 + 0] = x0.x; hreg[c4 * 8 + 1] = x0.y;
      hreg[c4 * 8 + 2] = x0.z; hreg[c4 * 8 + 3] = x0.w;
      hreg[c4 * 8 + 4] = x1.x; hreg[c4 * 8 + 5] = x1.y;
      hreg[c4 * 8 + 6] = x1.z; hreg[c4 * 8 + 7] = x1.w;
    }
    // 3 rows per thread: r-row (grp), z-row (16+grp), n-row (32+grp)
    float a0 = 0.f, a1 = 0.f, a2 = 0.f;
    const u16* wr0 = &sW[grp * 520 + l16 * 32];
    const u16* wr1 = wr0 + 16 * 520;
    const u16* wr2 = wr0 + 32 * 520;
    for (int c4 = 0; c4 < 4; ++c4) {
      uint4 w0 = *reinterpret_cast<const uint4*>(wr0 + c4 * 8);
      uint4 w1 = *reinterpret_cast<const uint4*>(wr1 + c4 * 8);
      uint4 w2 = *reinterpret_cast<const uint4*>(wr2 + c4 * 8);
      const float* hh = &hreg[c4 * 8];
      a0 += __uint_as_float(w0.x << 16) * hh[0] + __uint_as_float(w0.x & 0xffff0000u) * hh[1];
      a0 += __uint_as_float(w0.y << 16) * hh[2] + __uint_as_float(w0.y & 0xffff0000u) * hh[3];
      a0 += __uint_as_float(w0.z << 16) * hh[4] + __uint_as_float(w0.z & 0xffff0000u) * hh[5];
      a0 += __uint_as_float(w0.w << 16) * hh[6] + __uint_as_float(w0.w & 0xffff0000u) * hh[7];
      a1 += __uint_as_float(w1.x << 16) * hh[0] + __uint_as_float(w1.x & 0xffff0000u) * hh[1];
      a1 += __uint_as_float(w1.y << 16) * hh[2] + __uint_as_float(w1.y & 0xffff0000u) * hh[3];
      a1 += __uint_as_float(w1.z << 16) * hh[4] + __uint_as_float(w1.z & 0xffff0000u) * hh[5];
      a1 += __uint_as_float(w1.w << 16) * hh[6] + __uint_as_float(w1.w & 0xffff0000u) * hh[7];
      a2 += __uint_as_float(w2.x << 16) * hh[0] + __uint_as_float(w2.x & 0xffff0000u) * hh[1];
      a2 += __uint_as_float(w2.y << 16) * hh[2] + __uint_as_float(w2.y & 0xffff0000u) * hh[3];
      a2 += __uint_as_float(w2.z << 16) * hh[4] + __uint_as_float(w2.z & 0xffff0000u) * hh[5];
      a2 += __uint_as_float(w2.w << 16) * hh[6] + __uint_as_float(w2.w & 0xffff0000u) * hh[7];
    }
    for (int d = 1; d < 16; d <<= 1) {
      a0 += __shfl_xor(a0, d);
      a1 += __shfl_xor(a1, d);
      a2 += __shfl_xor(a2, d);
    }
    if (l16 == 0) {
      // fast sigmoid/tanh via v_exp + fast divide (saturation-safe)
      float er = __expf(-(gir + a0 + bhr));
      float ez = __expf(-(giz + a1 + bhz));
      float r = __fdividef(1.f, 1.f + er);
      float z = __fdividef(1.f, 1.f + ez);
      float xn = gin + r * (a2 + bhn);
      float en = __expf(2.f * xn);
      float n = 1.f - __fdividef(2.f, en + 1.f);   // tanh(xn); en=inf -> 1, en=0 -> -1
      float hprev = h_s[j + ((j >> 5) << 2)];
      float hv = (1.f - z) * n + z * hprev;
      __hip_atomic_store(hbase + (size_t)t * 8192 + b * 512 + j, __float_as_uint(hv),
                         __ATOMIC_RELAXED, __HIP_MEMORY_SCOPE_AGENT);
      ys[((size_t)b * 64 + t) * 512 + j] = f2bf(hv);
      if (t == 63) hlast[b * 512 + j] = hv;
    }
    __syncthreads();  // protect h_s before next step's overwrite
  }
}

// ---------- combine per-row LSE partials ----------
__global__ __launch_bounds__(64) void lse_combine_kernel(const float* __restrict__ partials,
                                                         float* __restrict__ lse, int nnb) {
  int row = blockIdx.x;
  int lane = threadIdx.x;
  float M = -INFINITY, S = 0.f;
  for (int i = lane; i < nnb; i += 64) {
    const float* p = partials + ((size_t)row * nnb + i) * 2;
    float m2 = p[0], s2 = p[1];
    if (m2 > M) { float tt = M; M = m2; m2 = tt; tt = S; S = s2; s2 = tt; }
    if (s2 > 0.f) S += s2 * __expf(m2 - M);
  }
  for (int d = 1; d < 64; d <<= 1) {
    float m2 = __shfl_xor(M, d), s2 = __shfl_xor(S, d);
    if (m2 > M) { float tt = M; M = m2; m2 = tt; tt = S; S = s2; s2 = tt; }
    if (s2 > 0.f) S += s2 * __expf(m2 - M);
  }
  if (lane == 0) lse[row] = M + logf(S);
}

// ---------- logp = logits - lse[row] ----------
__global__ __launch_bounds__(256) void sub_lse_kernel(float* __restrict__ out,
                                                      const float* __restrict__ lse) {
  int i = blockIdx.x * 256 + threadIdx.x;  // 8000 float4s per row
  int row = i / 8000;
  float l = lse[row];
  float4 v = reinterpret_cast<float4*>(out)[i];
  v.x -= l; v.y -= l; v.z -= l; v.w -= l;
  reinterpret_cast<float4*>(out)[i] = v;
}

extern "C" void kernel_launch(void* const* d_in, const int* in_sizes, int n_in,
                              void* d_out, int out_size, void* d_ws, size_t ws_size,
                              hipStream_t stream) {
  const int* tseq = (const int*)d_in[0];
  const float* thought = (const float*)d_in[1];
  const float* hidden = (const float*)d_in[2];
  const float* emb = (const float*)d_in[3];
  const float* W_ih = (const float*)d_in[4];
  const float* W_hh = (const float*)d_in[5];
  const float* b_ih = (const float*)d_in[6];
  const float* b_hh = (const float*)d_in[7];
  const float* W_out = (const float*)d_in[8];
  const float* b_out = (const float*)d_in[9];
  float* out = (float*)d_out;

  char* ws = (char*)d_ws;
  size_t off = 0;
  auto alloc = [&](size_t bytes) {
    void* p = ws + off;
    off = (off + bytes + 255) & ~(size_t)255;
    return p;
  };
  u16* wout_bf = (u16*)alloc((size_t)32000 * 512 * 2);
  u16* wih_bf  = (u16*)alloc((size_t)1536 * 1024 * 2);
  u16* x_bf    = (u16*)alloc((size_t)1024 * 1024 * 2);
  u16* ys_bf   = (u16*)alloc((size_t)1024 * 512 * 2);
  float* gi    = (float*)alloc((size_t)1024 * 1536 * 4);
  u32* hbase   = (u32*)alloc((size_t)64 * 16 * 512 * 4);
  float* partials = (float*)alloc((size_t)1024 * 250 * 2 * 4);
  float* lse   = (float*)alloc((size_t)1024 * 4);
  (void)ws_size; (void)in_sizes; (void)n_in; (void)out_size;

  hipMemsetAsync(hbase, 0xFF, (size_t)64 * 16 * 512 * 4, stream);  // NaN sentinel
  cvt_bf16_kernel<<<16000, 256, 0, stream>>>(W_out, wout_bf, 4096000);
  cvt_bf16_kernel<<<1536, 256, 0, stream>>>(W_ih, wih_bf, 393216);
  build_x_kernel<<<1024, 128, 0, stream>>>(tseq, emb, thought, x_bf);
  gemm_bt_kernel<false><<<dim3(12, 8), 256, 0, stream>>>(x_bf, wih_bf, b_ih, gi,
                                                         1024, 1536, 1024, nullptr, 0);
  gru_kernel<<<512, 256, 0, stream>>>(gi, W_hh, b_hh, hidden, hbase, ys_bf,
                                      out + 32768000);
  gemm_bt_kernel<true><<<dim3(250, 8), 256, 0, stream>>>(ys_bf, wout_bf, b_out, out,
                                                         1024, 32000, 512, partials, 250);
  lse_combine_kernel<<<1024, 64, 0, stream>>>(partials, lse, 250);
  sub_lse_kernel<<<32000, 256, 0, stream>>>(out, lse);
}

// Round 3
// 484.409 us; speedup vs baseline: 1.2160x; 1.0226x over previous
//
#include <hip/hip_runtime.h>

typedef unsigned int u32;
typedef unsigned short u16;
typedef short s16x8 __attribute__((ext_vector_type(8)));
typedef float f32x4 __attribute__((ext_vector_type(4)));

#define SENT 0xFFFFFFFFu

// ---------- helpers ----------
__device__ __forceinline__ u16 f2bf(float f) {
  u32 u = __float_as_uint(f);
  u32 r = (u + 0x7fffu + ((u >> 16) & 1u)) >> 16;  // RNE
  return (u16)r;
}

// L1/L2-bypassing 16B load (same cache path as agent-scope atomics)
__device__ __forceinline__ uint4 load_u4_bypass(const u32* p) {
  uint4 r;
  asm volatile("global_load_dwordx4 %0, %1, off sc0 sc1\n\ts_waitcnt vmcnt(0)"
               : "=v"(r) : "v"(p) : "memory");
  return r;
}

// ---------- fp32 -> bf16 convert (vectorized) ----------
__global__ __launch_bounds__(256) void cvt_bf16_kernel(const float* __restrict__ src,
                                                       u16* __restrict__ dst, int n4) {
  int i = blockIdx.x * 256 + threadIdx.x;
  if (i >= n4) return;
  float4 v = reinterpret_cast<const float4*>(src)[i];
  u32 lo = (u32)f2bf(v.x) | ((u32)f2bf(v.y) << 16);
  u32 hi = (u32)f2bf(v.z) | ((u32)f2bf(v.w) << 16);
  reinterpret_cast<uint2*>(dst)[i] = make_uint2(lo, hi);
}

// ---------- build x = [emb[tok] ; thought] as bf16, rows m = s*16+b, K=1024 ----------
__global__ __launch_bounds__(128) void build_x_kernel(const int* __restrict__ tseq,
                                                      const float* __restrict__ emb,
                                                      const float* __restrict__ thought,
                                                      u16* __restrict__ x) {
  int m = blockIdx.x;  // 0..1023, m = s*16 + b
  int s = m >> 4, b = m & 15;
  int tid = threadIdx.x;  // 128
  int k = tid * 8;
  const float* src;
  if (k < 512) src = emb + (size_t)tseq[b * 64 + s] * 512 + k;
  else         src = thought + b * 512 + (k - 512);
  float4 v0 = reinterpret_cast<const float4*>(src)[0];
  float4 v1 = reinterpret_cast<const float4*>(src)[1];
  uint4 o;
  o.x = (u32)f2bf(v0.x) | ((u32)f2bf(v0.y) << 16);
  o.y = (u32)f2bf(v0.z) | ((u32)f2bf(v0.w) << 16);
  o.z = (u32)f2bf(v1.x) | ((u32)f2bf(v1.y) << 16);
  o.w = (u32)f2bf(v1.z) | ((u32)f2bf(v1.w) << 16);
  *reinterpret_cast<uint4*>(x + (size_t)m * 1024 + k) = o;
}

// ---------- bf16 MFMA GEMM: C[M,N] = A[M,K] * B[N,K]^T + bias, optional LSE partials ----------
template <bool LSE>
__global__ __launch_bounds__(256) void gemm_bt_kernel(const u16* __restrict__ A,
                                                      const u16* __restrict__ Bm,
                                                      const float* __restrict__ bias,
                                                      float* __restrict__ C,
                                                      int M_, int N_, int K_,
                                                      float* __restrict__ partials, int nnb) {
  __shared__ u16 sA[128 * 40];
  __shared__ u16 sB[128 * 40];
  __shared__ float pm[2][128];
  __shared__ float ps[2][128];
  int nb = blockIdx.x, mb = blockIdx.y;
  int m0 = mb * 128, n0 = nb * 128;
  int tid = threadIdx.x;
  int wave = tid >> 6, lane = tid & 63;
  int wm = wave >> 1, wn = wave & 1;
  int l16 = lane & 15, quad = lane >> 4;
  int srow = tid >> 1, shalf = tid & 1;
  const u16* gA = A + (size_t)(m0 + srow) * K_ + shalf * 16;
  const u16* gB = Bm + (size_t)(n0 + srow) * K_ + shalf * 16;
  u16* lA = &sA[srow * 40 + shalf * 16];
  u16* lB = &sB[srow * 40 + shalf * 16];
  f32x4 acc[4][4];
  for (int i = 0; i < 4; ++i)
    for (int j = 0; j < 4; ++j) acc[i][j] = (f32x4){0.f, 0.f, 0.f, 0.f};

  for (int k0 = 0; k0 < K_; k0 += 32) {
    uint4 a0 = *reinterpret_cast<const uint4*>(gA + k0);
    uint4 a1 = *reinterpret_cast<const uint4*>(gA + k0 + 8);
    uint4 b0 = *reinterpret_cast<const uint4*>(gB + k0);
    uint4 b1 = *reinterpret_cast<const uint4*>(gB + k0 + 8);
    __syncthreads();
    *reinterpret_cast<uint4*>(lA) = a0;
    *reinterpret_cast<uint4*>(lA + 8) = a1;
    *reinterpret_cast<uint4*>(lB) = b0;
    *reinterpret_cast<uint4*>(lB + 8) = b1;
    __syncthreads();
    s16x8 af[4], bfr[4];
    for (int mt = 0; mt < 4; ++mt)
      af[mt] = *reinterpret_cast<const s16x8*>(&sA[(wm * 64 + mt * 16 + l16) * 40 + quad * 8]);
    for (int nt = 0; nt < 4; ++nt)
      bfr[nt] = *reinterpret_cast<const s16x8*>(&sB[(wn * 64 + nt * 16 + l16) * 40 + quad * 8]);
    for (int mt = 0; mt < 4; ++mt)
      for (int nt = 0; nt < 4; ++nt)
        acc[mt][nt] = __builtin_amdgcn_mfma_f32_16x16x32_bf16(af[mt], bfr[nt], acc[mt][nt], 0, 0, 0);
  }

  int rbase = wm * 64 + quad * 4;
  int cbase = n0 + wn * 64 + l16;
  for (int nt = 0; nt < 4; ++nt) {
    float bv = bias[cbase + nt * 16];
    for (int mt = 0; mt < 4; ++mt)
      for (int r = 0; r < 4; ++r) acc[mt][nt][r] += bv;
  }
  for (int mt = 0; mt < 4; ++mt)
    for (int r = 0; r < 4; ++r) {
      int row = m0 + rbase + mt * 16 + r;
      for (int nt = 0; nt < 4; ++nt)
        C[(size_t)row * N_ + cbase + nt * 16] = acc[mt][nt][r];
    }
  if (LSE) {
    for (int mt = 0; mt < 4; ++mt)
      for (int r = 0; r < 4; ++r) {
        float mx = acc[mt][0][r];
        for (int nt = 1; nt < 4; ++nt) mx = fmaxf(mx, acc[mt][nt][r]);
        for (int d = 1; d < 16; d <<= 1) mx = fmaxf(mx, __shfl_xor(mx, d));
        float sm = 0.f;
        for (int nt = 0; nt < 4; ++nt) sm += __expf(acc[mt][nt][r] - mx);
        for (int d = 1; d < 16; d <<= 1) sm += __shfl_xor(sm, d);
        if (l16 == 0) {
          int rr = wm * 64 + mt * 16 + quad * 4 + r;
          pm[wn][rr] = mx;
          ps[wn][rr] = sm;
        }
      }
    __syncthreads();
    if (tid < 128) {
      float m1 = pm[0][tid], m2 = pm[1][tid];
      float s1 = ps[0][tid], s2 = ps[1][tid];
      float Mx = fmaxf(m1, m2);
      float Sx = s1 * __expf(m1 - Mx) + s2 * __expf(m2 - Mx);
      float* p = partials + ((size_t)(m0 + tid) * nnb + nb) * 2;
      p[0] = Mx;
      p[1] = Sx;
    }
  }
}

// ---------- GRU recurrence + fused W_out converter ----------
// Grid 768: WGs 0..511 = recurrence (16 batches x 32 row-slices, 256 thr);
// WGs 512..767 = converter role (stream W_out f32->bf16 in the GRU's latency
// shadow). Safety: LDS 52224B -> 3 WGs/CU -> 768 slots >= 768 WGs, and
// __launch_bounds__(256,2) guarantees >=2 WGs/CU (512 slots) worst-case;
// converters terminate unconditionally, so worst dispatch order only delays
// some GRU WGs by the converter runtime (~25us), never deadlocks.
// Recurrence per WG: 16 row-groups (grp=tid>>4) x 16 lanes; group grp computes
// W_hh rows {grp,16+grp,32+grp} == r/z/n rows for output j=g*16+grp -> gates
// in-register after the 16-lane shuffle reduce.
// Sync (PROVEN two-phase): 32 lanes poll one flag word per writer slice ->
// barrier -> 128 threads bulk-read 16B each (sc0|sc1) with sentinel
// re-validation. 2 barriers/step: the phase-1 barrier (all 256 threads,
// unconditional for t>0) already orders step t's h_s reads (pre-barrier in
// every thread) against step t+1's phase-2 h_s writes (post-barrier), so no
// loop-end barrier is needed.
__global__ __launch_bounds__(256, 2) void gru_kernel(const float* __restrict__ gi,
                                                     const float* __restrict__ W_hh,
                                                     const float* __restrict__ b_hh,
                                                     const float* __restrict__ hidden,
                                                     u32* __restrict__ hbase,  // [64][16][512]
                                                     u16* __restrict__ ys,     // [1024][512], m=b*64+t
                                                     float* __restrict__ hlast,
                                                     const float* __restrict__ wout_f32,
                                                     u16* __restrict__ wout_bf) {
  __shared__ u16 sW[48 * 520];   // padded stride 520
  __shared__ float h_s[576];     // padded: idx(j) = j + 4*(j>>5)
  int wg = blockIdx.x;
  int tid = threadIdx.x;  // 256

  if (wg >= 512) {
    // ---- converter role: W_out f32 -> bf16 (4096000 float4s) ----
    for (int i = (wg - 512) * 256 + tid; i < 4096000; i += 256 * 256) {
      float4 v = reinterpret_cast<const float4*>(wout_f32)[i];
      u32 lo = (u32)f2bf(v.x) | ((u32)f2bf(v.y) << 16);
      u32 hi = (u32)f2bf(v.z) | ((u32)f2bf(v.w) << 16);
      reinterpret_cast<uint2*>(wout_bf)[i] = make_uint2(lo, hi);
    }
    return;
  }

  int b = wg >> 5, g = wg & 31;
  // stage W slice (48 rows x 512) as bf16 into LDS
  for (int e = tid * 4; e < 48 * 512; e += 1024) {
    int lr = e >> 9, col = e & 511;
    int grow = (lr >> 4) * 512 + g * 16 + (lr & 15);
    float4 v = *reinterpret_cast<const float4*>(W_hh + (size_t)grow * 512 + col);
    u32 lo = (u32)f2bf(v.x) | ((u32)f2bf(v.y) << 16);
    u32 hi = (u32)f2bf(v.z) | ((u32)f2bf(v.w) << 16);
    *reinterpret_cast<uint2*>(&sW[lr * 520 + col]) = make_uint2(lo, hi);
  }
  int grp = tid >> 4, l16 = tid & 15;
  int j = g * 16 + grp;                  // output index for writer lane (l16==0)
  float bhr = 0.f, bhz = 0.f, bhn = 0.f;
  if (l16 == 0) { bhr = b_hh[j]; bhz = b_hh[512 + j]; bhn = b_hh[1024 + j]; }
  int j0 = tid * 4;                      // bulk-read base (16B per thread, tid<128)
  // t=0 h_s fill, covered by the staging barrier
  if (tid < 128) {
    float4 f = *reinterpret_cast<const float4*>(hidden + b * 512 + j0);
    *reinterpret_cast<float4*>(&h_s[j0 + ((j0 >> 5) << 2)]) = f;
  }
  __syncthreads();

  for (int t = 0; t < 64; ++t) {
    // issue this step's gi loads early (independent of h_{t-1})
    float gir = 0.f, giz = 0.f, gin = 0.f;
    if (l16 == 0) {
      size_t gib = ((size_t)t * 16 + b) * 1536;
      gir = gi[gib + j]; giz = gi[gib + 512 + j]; gin = gi[gib + 1024 + j];
    }
    if (t > 0) {
      const u32* hp = hbase + (size_t)(t - 1) * 8192 + b * 512;
      // phase 1: 32 lanes poll one flag word per writer slice
      if (tid < 32) {
        const u32* fp = hp + tid * 16;
        u32 v = __hip_atomic_load(fp, __ATOMIC_RELAXED, __HIP_MEMORY_SCOPE_AGENT);
        while (v == SENT) {
          __builtin_amdgcn_s_sleep(2);
          v = __hip_atomic_load(fp, __ATOMIC_RELAXED, __HIP_MEMORY_SCOPE_AGENT);
        }
      }
      __syncthreads();  // also orders prev step's h_s reads vs phase-2 write below
      // phase 2: bulk read 16B/thread, validate sentinels
      if (tid < 128) {
        uint4 v = load_u4_bypass(hp + j0);
        while (v.x == SENT || v.y == SENT || v.z == SENT || v.w == SENT) {
          __builtin_amdgcn_s_sleep(1);
          v = load_u4_bypass(hp + j0);
        }
        float4 f;
        f.x = __uint_as_float(v.x); f.y = __uint_as_float(v.y);
        f.z = __uint_as_float(v.z); f.w = __uint_as_float(v.w);
        *reinterpret_cast<float4*>(&h_s[j0 + ((j0 >> 5) << 2)]) = f;
      }
      __syncthreads();
    }
    // preload this lane's 32 h values (cols l16*32..+32)
    float hreg[32];
    int hb2 = l16 * 36;
    for (int c4 = 0; c4 < 4; ++c4) {
      float4 x0 = *reinterpret_cast<const float4*>(&h_s[hb2 + c4 * 8]);
      float4 x1 = *reinterpret_cast<const float4*>(&h_s[hb2 + c4 * 8 + 4]);
      hreg[c4 * 8 + 0] = x0.x; hreg[c4 * 8 + 1] = x0.y;
      hreg[c4 * 8 + 2] = x0.z; hreg[c4 * 8 + 3] = x0.w;
      hreg[c4 * 8 + 4] = x1.x; hreg[c4 * 8 + 5] = x1.y;
      hreg[c4 * 8 + 6] = x1.z; hreg[c4 * 8 + 7] = x1.w;
    }
    // 3 rows per thread: r-row (grp), z-row (16+grp), n-row (32+grp)
    float a0 = 0.f, a1 = 0.f, a2 = 0.f;
    const u16* wr0 = &sW[grp * 520 + l16 * 32];
    const u16* wr1 = wr0 + 16 * 520;
    const u16* wr2 = wr0 + 32 * 520;
    for (int c4 = 0; c4 < 4; ++c4) {
      uint4 w0 = *reinterpret_cast<const uint4*>(wr0 + c4 * 8);
      uint4 w1 = *reinterpret_cast<const uint4*>(wr1 + c4 * 8);
      uint4 w2 = *reinterpret_cast<const uint4*>(wr2 + c4 * 8);
      const float* hh = &hreg[c4 * 8];
      a0 += __uint_as_float(w0.x << 16) * hh[0] + __uint_as_float(w0.x & 0xffff0000u) * hh[1];
      a0 += __uint_as_float(w0.y << 16) * hh[2] + __uint_as_float(w0.y & 0xffff0000u) * hh[3];
      a0 += __uint_as_float(w0.z << 16) * hh[4] + __uint_as_float(w0.z & 0xffff0000u) * hh[5];
      a0 += __uint_as_float(w0.w << 16) * hh[6] + __uint_as_float(w0.w & 0xffff0000u) * hh[7];
      a1 += __uint_as_float(w1.x << 16) * hh[0] + __uint_as_float(w1.x & 0xffff0000u) * hh[1];
      a1 += __uint_as_float(w1.y << 16) * hh[2] + __uint_as_float(w1.y & 0xffff0000u) * hh[3];
      a1 += __uint_as_float(w1.z << 16) * hh[4] + __uint_as_float(w1.z & 0xffff0000u) * hh[5];
      a1 += __uint_as_float(w1.w << 16) * hh[6] + __uint_as_float(w1.w & 0xffff0000u) * hh[7];
      a2 += __uint_as_float(w2.x << 16) * hh[0] + __uint_as_float(w2.x & 0xffff0000u) * hh[1];
      a2 += __uint_as_float(w2.y << 16) * hh[2] + __uint_as_float(w2.y & 0xffff0000u) * hh[3];
      a2 += __uint_as_float(w2.z << 16) * hh[4] + __uint_as_float(w2.z & 0xffff0000u) * hh[5];
      a2 += __uint_as_float(w2.w << 16) * hh[6] + __uint_as_float(w2.w & 0xffff0000u) * hh[7];
    }
    for (int d = 1; d < 16; d <<= 1) {
      a0 += __shfl_xor(a0, d);
      a1 += __shfl_xor(a1, d);
      a2 += __shfl_xor(a2, d);
    }
    if (l16 == 0) {
      // fast sigmoid/tanh via v_exp + fast divide (saturation-safe)
      float er = __expf(-(gir + a0 + bhr));
      float ez = __expf(-(giz + a1 + bhz));
      float r = __fdividef(1.f, 1.f + er);
      float z = __fdividef(1.f, 1.f + ez);
      float xn = gin + r * (a2 + bhn);
      float en = __expf(2.f * xn);
      float n = 1.f - __fdividef(2.f, en + 1.f);   // tanh(xn); en=inf -> 1, en=0 -> -1
      float hprev = h_s[j + ((j >> 5) << 2)];
      float hv = (1.f - z) * n + z * hprev;
      __hip_atomic_store(hbase + (size_t)t * 8192 + b * 512 + j, __float_as_uint(hv),
                         __ATOMIC_RELAXED, __HIP_MEMORY_SCOPE_AGENT);
      ys[((size_t)b * 64 + t) * 512 + j] = f2bf(hv);
      if (t == 63) hlast[b * 512 + j] = hv;
    }
    // no loop-end barrier: next step's phase-1 barrier provides the ordering
  }
}

// ---------- combine per-row LSE partials ----------
__global__ __launch_bounds__(64) void lse_combine_kernel(const float* __restrict__ partials,
                                                         float* __restrict__ lse, int nnb) {
  int row = blockIdx.x;
  int lane = threadIdx.x;
  float M = -INFINITY, S = 0.f;
  for (int i = lane; i < nnb; i += 64) {
    const float* p = partials + ((size_t)row * nnb + i) * 2;
    float m2 = p[0], s2 = p[1];
    if (m2 > M) { float tt = M; M = m2; m2 = tt; tt = S; S = s2; s2 = tt; }
    if (s2 > 0.f) S += s2 * __expf(m2 - M);
  }
  for (int d = 1; d < 64; d <<= 1) {
    float m2 = __shfl_xor(M, d), s2 = __shfl_xor(S, d);
    if (m2 > M) { float tt = M; M = m2; m2 = tt; tt = S; S = s2; s2 = tt; }
    if (s2 > 0.f) S += s2 * __expf(m2 - M);
  }
  if (lane == 0) lse[row] = M + logf(S);
}

// ---------- logp = logits - lse[row] ----------
__global__ __launch_bounds__(256) void sub_lse_kernel(float* __restrict__ out,
                                                      const float* __restrict__ lse) {
  int i = blockIdx.x * 256 + threadIdx.x;  // 8000 float4s per row
  int row = i / 8000;
  float l = lse[row];
  float4 v = reinterpret_cast<float4*>(out)[i];
  v.x -= l; v.y -= l; v.z -= l; v.w -= l;
  reinterpret_cast<float4*>(out)[i] = v;
}

extern "C" void kernel_launch(void* const* d_in, const int* in_sizes, int n_in,
                              void* d_out, int out_size, void* d_ws, size_t ws_size,
                              hipStream_t stream) {
  const int* tseq = (const int*)d_in[0];
  const float* thought = (const float*)d_in[1];
  const float* hidden = (const float*)d_in[2];
  const float* emb = (const float*)d_in[3];
  const float* W_ih = (const float*)d_in[4];
  const float* W_hh = (const float*)d_in[5];
  const float* b_ih = (const float*)d_in[6];
  const float* b_hh = (const float*)d_in[7];
  const float* W_out = (const float*)d_in[8];
  const float* b_out = (const float*)d_in[9];
  float* out = (float*)d_out;

  char* ws = (char*)d_ws;
  size_t off = 0;
  auto alloc = [&](size_t bytes) {
    void* p = ws + off;
    off = (off + bytes + 255) & ~(size_t)255;
    return p;
  };
  u16* wout_bf = (u16*)alloc((size_t)32000 * 512 * 2);
  u16* wih_bf  = (u16*)alloc((size_t)1536 * 1024 * 2);
  u16* x_bf    = (u16*)alloc((size_t)1024 * 1024 * 2);
  u16* ys_bf   = (u16*)alloc((size_t)1024 * 512 * 2);
  float* gi    = (float*)alloc((size_t)1024 * 1536 * 4);
  u32* hbase   = (u32*)alloc((size_t)64 * 16 * 512 * 4);
  float* partials = (float*)alloc((size_t)1024 * 250 * 2 * 4);
  float* lse   = (float*)alloc((size_t)1024 * 4);
  (void)ws_size; (void)in_sizes; (void)n_in; (void)out_size;

  hipMemsetAsync(hbase, 0xFF, (size_t)64 * 16 * 512 * 4, stream);  // NaN sentinel
  cvt_bf16_kernel<<<1536, 256, 0, stream>>>(W_ih, wih_bf, 393216);
  build_x_kernel<<<1024, 128, 0, stream>>>(tseq, emb, thought, x_bf);
  gemm_bt_kernel<false><<<dim3(12, 8), 256, 0, stream>>>(x_bf, wih_bf, b_ih, gi,
                                                         1024, 1536, 1024, nullptr, 0);
  // gru: 512 recurrence WGs + 256 converter WGs (W_out cvt hidden in latency shadow)
  gru_kernel<<<768, 256, 0, stream>>>(gi, W_hh, b_hh, hidden, hbase, ys_bf,
                                      out + 32768000, W_out, wout_bf);
  gemm_bt_kernel<true><<<dim3(250, 8), 256, 0, stream>>>(ys_bf, wout_bf, b_out, out,
                                                         1024, 32000, 512, partials, 250);
  lse_combine_kernel<<<1024, 64, 0, stream>>>(partials, lse, 250);
  sub_lse_kernel<<<32000, 256, 0, stream>>>(out, lse);
}

// Round 4
// 473.162 us; speedup vs baseline: 1.2449x; 1.0238x over previous
//
#include <hip/hip_runtime.h>

typedef unsigned int u32;
typedef unsigned short u16;
typedef short s16x8 __attribute__((ext_vector_type(8)));
typedef float f32x4 __attribute__((ext_vector_type(4)));

#define SENT 0xFFFFFFFFu

// ---------- helpers ----------
__device__ __forceinline__ u16 f2bf(float f) {
  u32 u = __float_as_uint(f);
  u32 r = (u + 0x7fffu + ((u >> 16) & 1u)) >> 16;  // RNE
  return (u16)r;
}

// L1/L2-bypassing 16B load (same cache path as agent-scope atomics)
__device__ __forceinline__ uint4 load_u4_bypass(const u32* p) {
  uint4 r;
  asm volatile("global_load_dwordx4 %0, %1, off sc0 sc1\n\ts_waitcnt vmcnt(0)"
               : "=v"(r) : "v"(p) : "memory");
  return r;
}

// async global->LDS, 16B per lane; LDS dest = wave-uniform base + lane*16
__device__ __forceinline__ void gload16(const u16* g, u16* l) {
  __builtin_amdgcn_global_load_lds(
      (const __attribute__((address_space(1))) unsigned int*)(g),
      (__attribute__((address_space(3))) unsigned int*)(l), 16, 0, 0);
}

// ---------- fp32 -> bf16 convert (vectorized) ----------
__global__ __launch_bounds__(256) void cvt_bf16_kernel(const float* __restrict__ src,
                                                       u16* __restrict__ dst, int n4) {
  int i = blockIdx.x * 256 + threadIdx.x;
  if (i >= n4) return;
  float4 v = reinterpret_cast<const float4*>(src)[i];
  u32 lo = (u32)f2bf(v.x) | ((u32)f2bf(v.y) << 16);
  u32 hi = (u32)f2bf(v.z) | ((u32)f2bf(v.w) << 16);
  reinterpret_cast<uint2*>(dst)[i] = make_uint2(lo, hi);
}

// ---------- build x = [emb[tok] ; thought] as bf16, rows m = s*16+b, K=1024 ----------
__global__ __launch_bounds__(128) void build_x_kernel(const int* __restrict__ tseq,
                                                      const float* __restrict__ emb,
                                                      const float* __restrict__ thought,
                                                      u16* __restrict__ x) {
  int m = blockIdx.x;  // 0..1023, m = s*16 + b
  int s = m >> 4, b = m & 15;
  int tid = threadIdx.x;  // 128
  int k = tid * 8;
  const float* src;
  if (k < 512) src = emb + (size_t)tseq[b * 64 + s] * 512 + k;
  else         src = thought + b * 512 + (k - 512);
  float4 v0 = reinterpret_cast<const float4*>(src)[0];
  float4 v1 = reinterpret_cast<const float4*>(src)[1];
  uint4 o;
  o.x = (u32)f2bf(v0.x) | ((u32)f2bf(v0.y) << 16);
  o.y = (u32)f2bf(v0.z) | ((u32)f2bf(v0.w) << 16);
  o.z = (u32)f2bf(v1.x) | ((u32)f2bf(v1.y) << 16);
  o.w = (u32)f2bf(v1.z) | ((u32)f2bf(v1.w) << 16);
  *reinterpret_cast<uint4*>(x + (size_t)m * 1024 + k) = o;
}

// ---------- bf16 MFMA GEMM (2-phase double-buffered global_load_lds pipeline) ----
// C[M,N] = A[M,K]*B[N,K]^T + bias, optional LSE partials.
// LDS: linear [128][32] tiles (global_load_lds requires linear dest).
// Staging: wave w loads chunk groups {2w,2w+1}; chunk c (16B) -> row c/4,
// cols (c%4)*8..+8; LDS byte off = c*16 = wave-uniform base + lane*16.
// Loop: STAGE(next buf) -> ds_read+MFMA(cur) -> one barrier (auto vmcnt drain).
template <bool LSE>
__global__ __launch_bounds__(256) void gemm_bt_kernel(const u16* __restrict__ A,
                                                      const u16* __restrict__ Bm,
                                                      const float* __restrict__ bias,
                                                      float* __restrict__ C,
                                                      int M_, int N_, int K_,
                                                      float* __restrict__ partials, int nnb) {
  __shared__ u16 sA[2][4096];
  __shared__ u16 sB[2][4096];
  __shared__ float pm[2][128];
  __shared__ float ps[2][128];
  int nb = blockIdx.x, mb = blockIdx.y;
  int m0 = mb * 128, n0 = nb * 128;
  int tid = threadIdx.x;
  int wave = tid >> 6, lane = tid & 63;
  int wm = wave >> 1, wn = wave & 1;
  int l16 = lane & 15, quad = lane >> 4;
  // staging geometry
  int c0 = wave * 128 + lane, c1 = c0 + 64;
  int r0 = c0 >> 2, co0 = (c0 & 3) * 8;
  int r1 = c1 >> 2, co1 = (c1 & 3) * 8;
  const u16* gA0 = A + (size_t)(m0 + r0) * K_ + co0;
  const u16* gA1 = A + (size_t)(m0 + r1) * K_ + co1;
  const u16* gB0 = Bm + (size_t)(n0 + r0) * K_ + co0;
  const u16* gB1 = Bm + (size_t)(n0 + r1) * K_ + co1;
  int wbase = wave * 1024;  // element base of wave's 2 groups in a buffer

  auto STAGE = [&](int buf, int k0) {
    gload16(gA0 + k0, &sA[buf][wbase]);
    gload16(gA1 + k0, &sA[buf][wbase + 512]);
    gload16(gB0 + k0, &sB[buf][wbase]);
    gload16(gB1 + k0, &sB[buf][wbase + 512]);
  };

  f32x4 acc[4][4];
  for (int i = 0; i < 4; ++i)
    for (int j = 0; j < 4; ++j) acc[i][j] = (f32x4){0.f, 0.f, 0.f, 0.f};

  int NK = K_ >> 5;
  STAGE(0, 0);
  __syncthreads();  // compiler drains vmcnt before barrier -> buf0 ready
  int cur = 0;
  for (int ks = 0; ks < NK; ++ks) {
    if (ks + 1 < NK) STAGE(cur ^ 1, (ks + 1) * 32);  // prefetch in flight during MFMA
    s16x8 af[4], bfr[4];
    for (int mt = 0; mt < 4; ++mt)
      af[mt] = *reinterpret_cast<const s16x8*>(&sA[cur][(wm * 64 + mt * 16 + l16) * 32 + quad * 8]);
    for (int nt = 0; nt < 4; ++nt)
      bfr[nt] = *reinterpret_cast<const s16x8*>(&sB[cur][(wn * 64 + nt * 16 + l16) * 32 + quad * 8]);
    for (int mt = 0; mt < 4; ++mt)
      for (int nt = 0; nt < 4; ++nt)
        acc[mt][nt] = __builtin_amdgcn_mfma_f32_16x16x32_bf16(af[mt], bfr[nt], acc[mt][nt], 0, 0, 0);
    if (ks + 1 < NK) {
      __syncthreads();  // drains vmcnt (next buf written) + lgkm (reads done)
      cur ^= 1;
    }
  }

  int rbase = wm * 64 + quad * 4;
  int cbase = n0 + wn * 64 + l16;
  for (int nt = 0; nt < 4; ++nt) {
    float bv = bias[cbase + nt * 16];
    for (int mt = 0; mt < 4; ++mt)
      for (int r = 0; r < 4; ++r) acc[mt][nt][r] += bv;
  }
  for (int mt = 0; mt < 4; ++mt)
    for (int r = 0; r < 4; ++r) {
      int row = m0 + rbase + mt * 16 + r;
      for (int nt = 0; nt < 4; ++nt)
        C[(size_t)row * N_ + cbase + nt * 16] = acc[mt][nt][r];
    }
  if (LSE) {
    for (int mt = 0; mt < 4; ++mt)
      for (int r = 0; r < 4; ++r) {
        float mx = acc[mt][0][r];
        for (int nt = 1; nt < 4; ++nt) mx = fmaxf(mx, acc[mt][nt][r]);
        for (int d = 1; d < 16; d <<= 1) mx = fmaxf(mx, __shfl_xor(mx, d));
        float sm = 0.f;
        for (int nt = 0; nt < 4; ++nt) sm += __expf(acc[mt][nt][r] - mx);
        for (int d = 1; d < 16; d <<= 1) sm += __shfl_xor(sm, d);
        if (l16 == 0) {
          int rr = wm * 64 + mt * 16 + quad * 4 + r;
          pm[wn][rr] = mx;
          ps[wn][rr] = sm;
        }
      }
    __syncthreads();
    if (tid < 128) {
      float m1 = pm[0][tid], m2 = pm[1][tid];
      float s1 = ps[0][tid], s2 = ps[1][tid];
      float Mx = fmaxf(m1, m2);
      float Sx = s1 * __expf(m1 - Mx) + s2 * __expf(m2 - Mx);
      float* p = partials + ((size_t)(m0 + tid) * nnb + nb) * 2;
      p[0] = Mx;
      p[1] = Sx;
    }
  }
}

// ---------- GRU recurrence + fused W_out converter (unchanged, proven) ----------
__global__ __launch_bounds__(256, 2) void gru_kernel(const float* __restrict__ gi,
                                                     const float* __restrict__ W_hh,
                                                     const float* __restrict__ b_hh,
                                                     const float* __restrict__ hidden,
                                                     u32* __restrict__ hbase,  // [64][16][512]
                                                     u16* __restrict__ ys,     // [1024][512], m=b*64+t
                                                     float* __restrict__ hlast,
                                                     const float* __restrict__ wout_f32,
                                                     u16* __restrict__ wout_bf) {
  __shared__ u16 sW[48 * 520];   // padded stride 520
  __shared__ float h_s[576];     // padded: idx(j) = j + 4*(j>>5)
  int wg = blockIdx.x;
  int tid = threadIdx.x;  // 256

  if (wg >= 512) {
    // ---- converter role: W_out f32 -> bf16 (4096000 float4s) ----
    for (int i = (wg - 512) * 256 + tid; i < 4096000; i += 256 * 256) {
      float4 v = reinterpret_cast<const float4*>(wout_f32)[i];
      u32 lo = (u32)f2bf(v.x) | ((u32)f2bf(v.y) << 16);
      u32 hi = (u32)f2bf(v.z) | ((u32)f2bf(v.w) << 16);
      reinterpret_cast<uint2*>(wout_bf)[i] = make_uint2(lo, hi);
    }
    return;
  }

  int b = wg >> 5, g = wg & 31;
  // stage W slice (48 rows x 512) as bf16 into LDS
  for (int e = tid * 4; e < 48 * 512; e += 1024) {
    int lr = e >> 9, col = e & 511;
    int grow = (lr >> 4) * 512 + g * 16 + (lr & 15);
    float4 v = *reinterpret_cast<const float4*>(W_hh + (size_t)grow * 512 + col);
    u32 lo = (u32)f2bf(v.x) | ((u32)f2bf(v.y) << 16);
    u32 hi = (u32)f2bf(v.z) | ((u32)f2bf(v.w) << 16);
    *reinterpret_cast<uint2*>(&sW[lr * 520 + col]) = make_uint2(lo, hi);
  }
  int grp = tid >> 4, l16 = tid & 15;
  int j = g * 16 + grp;                  // output index for writer lane (l16==0)
  float bhr = 0.f, bhz = 0.f, bhn = 0.f;
  if (l16 == 0) { bhr = b_hh[j]; bhz = b_hh[512 + j]; bhn = b_hh[1024 + j]; }
  int j0 = tid * 4;                      // bulk-read base (16B per thread, tid<128)
  // t=0 h_s fill, covered by the staging barrier
  if (tid < 128) {
    float4 f = *reinterpret_cast<const float4*>(hidden + b * 512 + j0);
    *reinterpret_cast<float4*>(&h_s[j0 + ((j0 >> 5) << 2)]) = f;
  }
  __syncthreads();

  for (int t = 0; t < 64; ++t) {
    // issue this step's gi loads early (independent of h_{t-1})
    float gir = 0.f, giz = 0.f, gin = 0.f;
    if (l16 == 0) {
      size_t gib = ((size_t)t * 16 + b) * 1536;
      gir = gi[gib + j]; giz = gi[gib + 512 + j]; gin = gi[gib + 1024 + j];
    }
    if (t > 0) {
      const u32* hp = hbase + (size_t)(t - 1) * 8192 + b * 512;
      // phase 1: 32 lanes poll one flag word per writer slice
      if (tid < 32) {
        const u32* fp = hp + tid * 16;
        u32 v = __hip_atomic_load(fp, __ATOMIC_RELAXED, __HIP_MEMORY_SCOPE_AGENT);
        while (v == SENT) {
          __builtin_amdgcn_s_sleep(2);
          v = __hip_atomic_load(fp, __ATOMIC_RELAXED, __HIP_MEMORY_SCOPE_AGENT);
        }
      }
      __syncthreads();  // also orders prev step's h_s reads vs phase-2 write below
      // phase 2: bulk read 16B/thread, validate sentinels
      if (tid < 128) {
        uint4 v = load_u4_bypass(hp + j0);
        while (v.x == SENT || v.y == SENT || v.z == SENT || v.w == SENT) {
          __builtin_amdgcn_s_sleep(1);
          v = load_u4_bypass(hp + j0);
        }
        float4 f;
        f.x = __uint_as_float(v.x); f.y = __uint_as_float(v.y);
        f.z = __uint_as_float(v.z); f.w = __uint_as_float(v.w);
        *reinterpret_cast<float4*>(&h_s[j0 + ((j0 >> 5) << 2)]) = f;
      }
      __syncthreads();
    }
    // preload this lane's 32 h values (cols l16*32..+32)
    float hreg[32];
    int hb2 = l16 * 36;
    for (int c4 = 0; c4 < 4; ++c4) {
      float4 x0 = *reinterpret_cast<const float4*>(&h_s[hb2 + c4 * 8]);
      float4 x1 = *reinterpret_cast<const float4*>(&h_s[hb2 + c4 * 8 + 4]);
      hreg[c4 * 8 + 0] = x0.x; hreg[c4 * 8 + 1] = x0.y;
      hreg[c4 * 8 + 2] = x0.z; hreg[c4 * 8 + 3] = x0.w;
      hreg[c4 * 8 + 4] = x1.x; hreg[c4 * 8 + 5] = x1.y;
      hreg[c4 * 8 + 6] = x1.z; hreg[c4 * 8 + 7] = x1.w;
    }
    // 3 rows per thread: r-row (grp), z-row (16+grp), n-row (32+grp)
    float a0 = 0.f, a1 = 0.f, a2 = 0.f;
    const u16* wr0 = &sW[grp * 520 + l16 * 32];
    const u16* wr1 = wr0 + 16 * 520;
    const u16* wr2 = wr0 + 32 * 520;
    for (int c4 = 0; c4 < 4; ++c4) {
      uint4 w0 = *reinterpret_cast<const uint4*>(wr0 + c4 * 8);
      uint4 w1 = *reinterpret_cast<const uint4*>(wr1 + c4 * 8);
      uint4 w2 = *reinterpret_cast<const uint4*>(wr2 + c4 * 8);
      const float* hh = &hreg[c4 * 8];
      a0 += __uint_as_float(w0.x << 16) * hh[0] + __uint_as_float(w0.x & 0xffff0000u) * hh[1];
      a0 += __uint_as_float(w0.y << 16) * hh[2] + __uint_as_float(w0.y & 0xffff0000u) * hh[3];
      a0 += __uint_as_float(w0.z << 16) * hh[4] + __uint_as_float(w0.z & 0xffff0000u) * hh[5];
      a0 += __uint_as_float(w0.w << 16) * hh[6] + __uint_as_float(w0.w & 0xffff0000u) * hh[7];
      a1 += __uint_as_float(w1.x << 16) * hh[0] + __uint_as_float(w1.x & 0xffff0000u) * hh[1];
      a1 += __uint_as_float(w1.y << 16) * hh[2] + __uint_as_float(w1.y & 0xffff0000u) * hh[3];
      a1 += __uint_as_float(w1.z << 16) * hh[4] + __uint_as_float(w1.z & 0xffff0000u) * hh[5];
      a1 += __uint_as_float(w1.w << 16) * hh[6] + __uint_as_float(w1.w & 0xffff0000u) * hh[7];
      a2 += __uint_as_float(w2.x << 16) * hh[0] + __uint_as_float(w2.x & 0xffff0000u) * hh[1];
      a2 += __uint_as_float(w2.y << 16) * hh[2] + __uint_as_float(w2.y & 0xffff0000u) * hh[3];
      a2 += __uint_as_float(w2.z << 16) * hh[4] + __uint_as_float(w2.z & 0xffff0000u) * hh[5];
      a2 += __uint_as_float(w2.w << 16) * hh[6] + __uint_as_float(w2.w & 0xffff0000u) * hh[7];
    }
    for (int d = 1; d < 16; d <<= 1) {
      a0 += __shfl_xor(a0, d);
      a1 += __shfl_xor(a1, d);
      a2 += __shfl_xor(a2, d);
    }
    if (l16 == 0) {
      // fast sigmoid/tanh via v_exp + fast divide (saturation-safe)
      float er = __expf(-(gir + a0 + bhr));
      float ez = __expf(-(giz + a1 + bhz));
      float r = __fdividef(1.f, 1.f + er);
      float z = __fdividef(1.f, 1.f + ez);
      float xn = gin + r * (a2 + bhn);
      float en = __expf(2.f * xn);
      float n = 1.f - __fdividef(2.f, en + 1.f);   // tanh(xn); en=inf -> 1, en=0 -> -1
      float hprev = h_s[j + ((j >> 5) << 2)];
      float hv = (1.f - z) * n + z * hprev;
      __hip_atomic_store(hbase + (size_t)t * 8192 + b * 512 + j, __float_as_uint(hv),
                         __ATOMIC_RELAXED, __HIP_MEMORY_SCOPE_AGENT);
      ys[((size_t)b * 64 + t) * 512 + j] = f2bf(hv);
      if (t == 63) hlast[b * 512 + j] = hv;
    }
    // no loop-end barrier: next step's phase-1 barrier provides the ordering
  }
}

// ---------- combine per-row LSE partials ----------
__global__ __launch_bounds__(64) void lse_combine_kernel(const float* __restrict__ partials,
                                                         float* __restrict__ lse, int nnb) {
  int row = blockIdx.x;
  int lane = threadIdx.x;
  float M = -INFINITY, S = 0.f;
  for (int i = lane; i < nnb; i += 64) {
    const float* p = partials + ((size_t)row * nnb + i) * 2;
    float m2 = p[0], s2 = p[1];
    if (m2 > M) { float tt = M; M = m2; m2 = tt; tt = S; S = s2; s2 = tt; }
    if (s2 > 0.f) S += s2 * __expf(m2 - M);
  }
  for (int d = 1; d < 64; d <<= 1) {
    float m2 = __shfl_xor(M, d), s2 = __shfl_xor(S, d);
    if (m2 > M) { float tt = M; M = m2; m2 = tt; tt = S; S = s2; s2 = tt; }
    if (s2 > 0.f) S += s2 * __expf(m2 - M);
  }
  if (lane == 0) lse[row] = M + logf(S);
}

// ---------- logp = logits - lse[row] ----------
__global__ __launch_bounds__(256) void sub_lse_kernel(float* __restrict__ out,
                                                      const float* __restrict__ lse) {
  int i = blockIdx.x * 256 + threadIdx.x;  // 8000 float4s per row
  int row = i / 8000;
  float l = lse[row];
  float4 v = reinterpret_cast<float4*>(out)[i];
  v.x -= l; v.y -= l; v.z -= l; v.w -= l;
  reinterpret_cast<float4*>(out)[i] = v;
}

extern "C" void kernel_launch(void* const* d_in, const int* in_sizes, int n_in,
                              void* d_out, int out_size, void* d_ws, size_t ws_size,
                              hipStream_t stream) {
  const int* tseq = (const int*)d_in[0];
  const float* thought = (const float*)d_in[1];
  const float* hidden = (const float*)d_in[2];
  const float* emb = (const float*)d_in[3];
  const float* W_ih = (const float*)d_in[4];
  const float* W_hh = (const float*)d_in[5];
  const float* b_ih = (const float*)d_in[6];
  const float* b_hh = (const float*)d_in[7];
  const float* W_out = (const float*)d_in[8];
  const float* b_out = (const float*)d_in[9];
  float* out = (float*)d_out;

  char* ws = (char*)d_ws;
  size_t off = 0;
  auto alloc = [&](size_t bytes) {
    void* p = ws + off;
    off = (off + bytes + 255) & ~(size_t)255;
    return p;
  };
  u16* wout_bf = (u16*)alloc((size_t)32000 * 512 * 2);
  u16* wih_bf  = (u16*)alloc((size_t)1536 * 1024 * 2);
  u16* x_bf    = (u16*)alloc((size_t)1024 * 1024 * 2);
  u16* ys_bf   = (u16*)alloc((size_t)1024 * 512 * 2);
  float* gi    = (float*)alloc((size_t)1024 * 1536 * 4);
  u32* hbase   = (u32*)alloc((size_t)64 * 16 * 512 * 4);
  float* partials = (float*)alloc((size_t)1024 * 250 * 2 * 4);
  float* lse   = (float*)alloc((size_t)1024 * 4);
  (void)ws_size; (void)in_sizes; (void)n_in; (void)out_size;

  hipMemsetAsync(hbase, 0xFF, (size_t)64 * 16 * 512 * 4, stream);  // NaN sentinel
  cvt_bf16_kernel<<<1536, 256, 0, stream>>>(W_ih, wih_bf, 393216);
  build_x_kernel<<<1024, 128, 0, stream>>>(tseq, emb, thought, x_bf);
  gemm_bt_kernel<false><<<dim3(12, 8), 256, 0, stream>>>(x_bf, wih_bf, b_ih, gi,
                                                         1024, 1536, 1024, nullptr, 0);
  // gru: 512 recurrence WGs + 256 converter WGs (W_out cvt hidden in latency shadow)
  gru_kernel<<<768, 256, 0, stream>>>(gi, W_hh, b_hh, hidden, hbase, ys_bf,
                                      out + 32768000, W_out, wout_bf);
  gemm_bt_kernel<true><<<dim3(250, 8), 256, 0, stream>>>(ys_bf, wout_bf, b_out, out,
                                                         1024, 32000, 512, partials, 250);
  lse_combine_kernel<<<1024, 64, 0, stream>>>(partials, lse, 250);
  sub_lse_kernel<<<32000, 256, 0, stream>>>(out, lse);
}

// Round 5
// 460.926 us; speedup vs baseline: 1.2779x; 1.0265x over previous
//
#include <hip/hip_runtime.h>

typedef unsigned int u32;
typedef unsigned short u16;
typedef short s16x8 __attribute__((ext_vector_type(8)));
typedef float f32x4 __attribute__((ext_vector_type(4)));

#define SENT 0xFFFFFFFFu

// ---------- helpers ----------
__device__ __forceinline__ u16 f2bf(float f) {
  u32 u = __float_as_uint(f);
  u32 r = (u + 0x7fffu + ((u >> 16) & 1u)) >> 16;  // RNE
  return (u16)r;
}

// L1/L2-bypassing 16B load (same cache path as agent-scope atomics)
__device__ __forceinline__ uint4 load_u4_bypass(const u32* p) {
  uint4 r;
  asm volatile("global_load_dwordx4 %0, %1, off sc0 sc1\n\ts_waitcnt vmcnt(0)"
               : "=v"(r) : "v"(p) : "memory");
  return r;
}

// async global->LDS, 16B per lane; LDS dest = wave-uniform base + lane*16
__device__ __forceinline__ void gload16(const u16* g, u16* l) {
  __builtin_amdgcn_global_load_lds(
      (const __attribute__((address_space(1))) unsigned int*)(g),
      (__attribute__((address_space(3))) unsigned int*)(l), 16, 0, 0);
}

// ---------- fused pre-pass: cvt W_ih + build_x + hbase sentinel fill ----------
// Roles by blockIdx (disjoint outputs, no inter-role ordering needed):
//   [0,1536)    : W_ih f32->bf16 (393216 float4s)
//   [1536,2560) : build x row m = blk-1536 (m = s*16+b, K=1024)
//   [2560,3072) : hbase = SENT (131072 uint4s)
__global__ __launch_bounds__(256) void pre_kernel(const float* __restrict__ W_ih,
                                                  u16* __restrict__ wih_bf,
                                                  const int* __restrict__ tseq,
                                                  const float* __restrict__ emb,
                                                  const float* __restrict__ thought,
                                                  u16* __restrict__ x,
                                                  u32* __restrict__ hbase) {
  int blk = blockIdx.x, tid = threadIdx.x;
  if (blk < 1536) {
    int i = blk * 256 + tid;
    float4 v = reinterpret_cast<const float4*>(W_ih)[i];
    u32 lo = (u32)f2bf(v.x) | ((u32)f2bf(v.y) << 16);
    u32 hi = (u32)f2bf(v.z) | ((u32)f2bf(v.w) << 16);
    reinterpret_cast<uint2*>(wih_bf)[i] = make_uint2(lo, hi);
  } else if (blk < 2560) {
    int m = blk - 1536;          // 0..1023
    int s = m >> 4, b = m & 15;
    int k = tid * 4;             // 4 elems/thread, K=1024
    const float* src = (k < 512) ? emb + (size_t)tseq[b * 64 + s] * 512 + k
                                 : thought + b * 512 + (k - 512);
    float4 v = *reinterpret_cast<const float4*>(src);
    *reinterpret_cast<uint2*>(x + (size_t)m * 1024 + k) =
        make_uint2((u32)f2bf(v.x) | ((u32)f2bf(v.y) << 16),
                   (u32)f2bf(v.z) | ((u32)f2bf(v.w) << 16));
  } else {
    int i = (blk - 2560) * 256 + tid;   // 512 blks * 256 * 16B = 2 MB
    reinterpret_cast<uint4*>(hbase)[i] = make_uint4(SENT, SENT, SENT, SENT);
  }
}

// ---------- bf16 MFMA GEMM (2-phase double-buffered global_load_lds pipeline) ----
// C[M,N] = A[M,K]*B[N,K]^T + bias, optional LSE partials. 1-D grid, M_=1024.
// XCD-bijective swizzle (m204, mb-fastest decode): XCD k gets a contiguous
// nb-chunk x all 8 mb -> a B stripe is fetched from HBM once per XCD instead
// of up to 8x (B reuse in per-XCD L2). Requires gridDim.x % 8 == 0 (96, 2000 ok).
template <bool LSE>
__global__ __launch_bounds__(256) void gemm_bt_kernel(const u16* __restrict__ A,
                                                      const u16* __restrict__ Bm,
                                                      const float* __restrict__ bias,
                                                      float* __restrict__ C,
                                                      int M_, int N_, int K_,
                                                      float* __restrict__ partials, int nnb) {
  __shared__ u16 sA[2][4096];
  __shared__ u16 sB[2][4096];
  __shared__ float pm[2][128];
  __shared__ float ps[2][128];
  int bid = blockIdx.x;
  int nwg8 = gridDim.x >> 3;
  int wgid = (bid & 7) * nwg8 + (bid >> 3);  // bijective XCD swizzle
  int mb = wgid & 7, nb = wgid >> 3;         // mb fastest within XCD chunk
  int m0 = mb * 128, n0 = nb * 128;
  int tid = threadIdx.x;
  int wave = tid >> 6, lane = tid & 63;
  int wm = wave >> 1, wn = wave & 1;
  int l16 = lane & 15, quad = lane >> 4;
  // staging geometry
  int c0 = wave * 128 + lane, c1 = c0 + 64;
  int r0 = c0 >> 2, co0 = (c0 & 3) * 8;
  int r1 = c1 >> 2, co1 = (c1 & 3) * 8;
  const u16* gA0 = A + (size_t)(m0 + r0) * K_ + co0;
  const u16* gA1 = A + (size_t)(m0 + r1) * K_ + co1;
  const u16* gB0 = Bm + (size_t)(n0 + r0) * K_ + co0;
  const u16* gB1 = Bm + (size_t)(n0 + r1) * K_ + co1;
  int wbase = wave * 1024;  // element base of wave's 2 groups in a buffer

  auto STAGE = [&](int buf, int k0) {
    gload16(gA0 + k0, &sA[buf][wbase]);
    gload16(gA1 + k0, &sA[buf][wbase + 512]);
    gload16(gB0 + k0, &sB[buf][wbase]);
    gload16(gB1 + k0, &sB[buf][wbase + 512]);
  };

  f32x4 acc[4][4];
  for (int i = 0; i < 4; ++i)
    for (int j = 0; j < 4; ++j) acc[i][j] = (f32x4){0.f, 0.f, 0.f, 0.f};

  int NK = K_ >> 5;
  STAGE(0, 0);
  __syncthreads();  // compiler drains vmcnt before barrier -> buf0 ready
  int cur = 0;
  for (int ks = 0; ks < NK; ++ks) {
    if (ks + 1 < NK) STAGE(cur ^ 1, (ks + 1) * 32);  // prefetch in flight during MFMA
    s16x8 af[4], bfr[4];
    for (int mt = 0; mt < 4; ++mt)
      af[mt] = *reinterpret_cast<const s16x8*>(&sA[cur][(wm * 64 + mt * 16 + l16) * 32 + quad * 8]);
    for (int nt = 0; nt < 4; ++nt)
      bfr[nt] = *reinterpret_cast<const s16x8*>(&sB[cur][(wn * 64 + nt * 16 + l16) * 32 + quad * 8]);
    for (int mt = 0; mt < 4; ++mt)
      for (int nt = 0; nt < 4; ++nt)
        acc[mt][nt] = __builtin_amdgcn_mfma_f32_16x16x32_bf16(af[mt], bfr[nt], acc[mt][nt], 0, 0, 0);
    if (ks + 1 < NK) {
      __syncthreads();  // drains vmcnt (next buf written) + lgkm (reads done)
      cur ^= 1;
    }
  }

  int rbase = wm * 64 + quad * 4;
  int cbase = n0 + wn * 64 + l16;
  for (int nt = 0; nt < 4; ++nt) {
    float bv = bias[cbase + nt * 16];
    for (int mt = 0; mt < 4; ++mt)
      for (int r = 0; r < 4; ++r) acc[mt][nt][r] += bv;
  }
  for (int mt = 0; mt < 4; ++mt)
    for (int r = 0; r < 4; ++r) {
      int row = m0 + rbase + mt * 16 + r;
      for (int nt = 0; nt < 4; ++nt)
        C[(size_t)row * N_ + cbase + nt * 16] = acc[mt][nt][r];
    }
  if (LSE) {
    for (int mt = 0; mt < 4; ++mt)
      for (int r = 0; r < 4; ++r) {
        float mx = acc[mt][0][r];
        for (int nt = 1; nt < 4; ++nt) mx = fmaxf(mx, acc[mt][nt][r]);
        for (int d = 1; d < 16; d <<= 1) mx = fmaxf(mx, __shfl_xor(mx, d));
        float sm = 0.f;
        for (int nt = 0; nt < 4; ++nt) sm += __expf(acc[mt][nt][r] - mx);
        for (int d = 1; d < 16; d <<= 1) sm += __shfl_xor(sm, d);
        if (l16 == 0) {
          int rr = wm * 64 + mt * 16 + quad * 4 + r;
          pm[wn][rr] = mx;
          ps[wn][rr] = sm;
        }
      }
    __syncthreads();
    if (tid < 128) {
      float m1 = pm[0][tid], m2 = pm[1][tid];
      float s1 = ps[0][tid], s2 = ps[1][tid];
      float Mx = fmaxf(m1, m2);
      float Sx = s1 * __expf(m1 - Mx) + s2 * __expf(m2 - Mx);
      float* p = partials + ((size_t)(m0 + tid) * nnb + nb) * 2;
      p[0] = Mx;
      p[1] = Sx;
    }
  }
}

// ---------- GRU recurrence + fused W_out converter (unchanged, proven) ----------
__global__ __launch_bounds__(256, 2) void gru_kernel(const float* __restrict__ gi,
                                                     const float* __restrict__ W_hh,
                                                     const float* __restrict__ b_hh,
                                                     const float* __restrict__ hidden,
                                                     u32* __restrict__ hbase,  // [64][16][512]
                                                     u16* __restrict__ ys,     // [1024][512], m=b*64+t
                                                     float* __restrict__ hlast,
                                                     const float* __restrict__ wout_f32,
                                                     u16* __restrict__ wout_bf) {
  __shared__ u16 sW[48 * 520];   // padded stride 520
  __shared__ float h_s[576];     // padded: idx(j) = j + 4*(j>>5)
  int wg = blockIdx.x;
  int tid = threadIdx.x;  // 256

  if (wg >= 512) {
    // ---- converter role: W_out f32 -> bf16 (4096000 float4s) ----
    for (int i = (wg - 512) * 256 + tid; i < 4096000; i += 256 * 256) {
      float4 v = reinterpret_cast<const float4*>(wout_f32)[i];
      u32 lo = (u32)f2bf(v.x) | ((u32)f2bf(v.y) << 16);
      u32 hi = (u32)f2bf(v.z) | ((u32)f2bf(v.w) << 16);
      reinterpret_cast<uint2*>(wout_bf)[i] = make_uint2(lo, hi);
    }
    return;
  }

  int b = wg >> 5, g = wg & 31;
  // stage W slice (48 rows x 512) as bf16 into LDS
  for (int e = tid * 4; e < 48 * 512; e += 1024) {
    int lr = e >> 9, col = e & 511;
    int grow = (lr >> 4) * 512 + g * 16 + (lr & 15);
    float4 v = *reinterpret_cast<const float4*>(W_hh + (size_t)grow * 512 + col);
    u32 lo = (u32)f2bf(v.x) | ((u32)f2bf(v.y) << 16);
    u32 hi = (u32)f2bf(v.z) | ((u32)f2bf(v.w) << 16);
    *reinterpret_cast<uint2*>(&sW[lr * 520 + col]) = make_uint2(lo, hi);
  }
  int grp = tid >> 4, l16 = tid & 15;
  int j = g * 16 + grp;                  // output index for writer lane (l16==0)
  float bhr = 0.f, bhz = 0.f, bhn = 0.f;
  if (l16 == 0) { bhr = b_hh[j]; bhz = b_hh[512 + j]; bhn = b_hh[1024 + j]; }
  int j0 = tid * 4;                      // bulk-read base (16B per thread, tid<128)
  // t=0 h_s fill, covered by the staging barrier
  if (tid < 128) {
    float4 f = *reinterpret_cast<const float4*>(hidden + b * 512 + j0);
    *reinterpret_cast<float4*>(&h_s[j0 + ((j0 >> 5) << 2)]) = f;
  }
  __syncthreads();

  for (int t = 0; t < 64; ++t) {
    // issue this step's gi loads early (independent of h_{t-1})
    float gir = 0.f, giz = 0.f, gin = 0.f;
    if (l16 == 0) {
      size_t gib = ((size_t)t * 16 + b) * 1536;
      gir = gi[gib + j]; giz = gi[gib + 512 + j]; gin = gi[gib + 1024 + j];
    }
    if (t > 0) {
      const u32* hp = hbase + (size_t)(t - 1) * 8192 + b * 512;
      // phase 1: 32 lanes poll one flag word per writer slice
      if (tid < 32) {
        const u32* fp = hp + tid * 16;
        u32 v = __hip_atomic_load(fp, __ATOMIC_RELAXED, __HIP_MEMORY_SCOPE_AGENT);
        while (v == SENT) {
          __builtin_amdgcn_s_sleep(2);
          v = __hip_atomic_load(fp, __ATOMIC_RELAXED, __HIP_MEMORY_SCOPE_AGENT);
        }
      }
      __syncthreads();  // also orders prev step's h_s reads vs phase-2 write below
      // phase 2: bulk read 16B/thread, validate sentinels
      if (tid < 128) {
        uint4 v = load_u4_bypass(hp + j0);
        while (v.x == SENT || v.y == SENT || v.z == SENT || v.w == SENT) {
          __builtin_amdgcn_s_sleep(1);
          v = load_u4_bypass(hp + j0);
        }
        float4 f;
        f.x = __uint_as_float(v.x); f.y = __uint_as_float(v.y);
        f.z = __uint_as_float(v.z); f.w = __uint_as_float(v.w);
        *reinterpret_cast<float4*>(&h_s[j0 + ((j0 >> 5) << 2)]) = f;
      }
      __syncthreads();
    }
    // preload this lane's 32 h values (cols l16*32..+32)
    float hreg[32];
    int hb2 = l16 * 36;
    for (int c4 = 0; c4 < 4; ++c4) {
      float4 x0 = *reinterpret_cast<const float4*>(&h_s[hb2 + c4 * 8]);
      float4 x1 = *reinterpret_cast<const float4*>(&h_s[hb2 + c4 * 8 + 4]);
      hreg[c4 * 8 + 0] = x0.x; hreg[c4 * 8 + 1] = x0.y;
      hreg[c4 * 8 + 2] = x0.z; hreg[c4 * 8 + 3] = x0.w;
      hreg[c4 * 8 + 4] = x1.x; hreg[c4 * 8 + 5] = x1.y;
      hreg[c4 * 8 + 6] = x1.z; hreg[c4 * 8 + 7] = x1.w;
    }
    // 3 rows per thread: r-row (grp), z-row (16+grp), n-row (32+grp)
    float a0 = 0.f, a1 = 0.f, a2 = 0.f;
    const u16* wr0 = &sW[grp * 520 + l16 * 32];
    const u16* wr1 = wr0 + 16 * 520;
    const u16* wr2 = wr0 + 32 * 520;
    for (int c4 = 0; c4 < 4; ++c4) {
      uint4 w0 = *reinterpret_cast<const uint4*>(wr0 + c4 * 8);
      uint4 w1 = *reinterpret_cast<const uint4*>(wr1 + c4 * 8);
      uint4 w2 = *reinterpret_cast<const uint4*>(wr2 + c4 * 8);
      const float* hh = &hreg[c4 * 8];
      a0 += __uint_as_float(w0.x << 16) * hh[0] + __uint_as_float(w0.x & 0xffff0000u) * hh[1];
      a0 += __uint_as_float(w0.y << 16) * hh[2] + __uint_as_float(w0.y & 0xffff0000u) * hh[3];
      a0 += __uint_as_float(w0.z << 16) * hh[4] + __uint_as_float(w0.z & 0xffff0000u) * hh[5];
      a0 += __uint_as_float(w0.w << 16) * hh[6] + __uint_as_float(w0.w & 0xffff0000u) * hh[7];
      a1 += __uint_as_float(w1.x << 16) * hh[0] + __uint_as_float(w1.x & 0xffff0000u) * hh[1];
      a1 += __uint_as_float(w1.y << 16) * hh[2] + __uint_as_float(w1.y & 0xffff0000u) * hh[3];
      a1 += __uint_as_float(w1.z << 16) * hh[4] + __uint_as_float(w1.z & 0xffff0000u) * hh[5];
      a1 += __uint_as_float(w1.w << 16) * hh[6] + __uint_as_float(w1.w & 0xffff0000u) * hh[7];
      a2 += __uint_as_float(w2.x << 16) * hh[0] + __uint_as_float(w2.x & 0xffff0000u) * hh[1];
      a2 += __uint_as_float(w2.y << 16) * hh[2] + __uint_as_float(w2.y & 0xffff0000u) * hh[3];
      a2 += __uint_as_float(w2.z << 16) * hh[4] + __uint_as_float(w2.z & 0xffff0000u) * hh[5];
      a2 += __uint_as_float(w2.w << 16) * hh[6] + __uint_as_float(w2.w & 0xffff0000u) * hh[7];
    }
    for (int d = 1; d < 16; d <<= 1) {
      a0 += __shfl_xor(a0, d);
      a1 += __shfl_xor(a1, d);
      a2 += __shfl_xor(a2, d);
    }
    if (l16 == 0) {
      // fast sigmoid/tanh via v_exp + fast divide (saturation-safe)
      float er = __expf(-(gir + a0 + bhr));
      float ez = __expf(-(giz + a1 + bhz));
      float r = __fdividef(1.f, 1.f + er);
      float z = __fdividef(1.f, 1.f + ez);
      float xn = gin + r * (a2 + bhn);
      float en = __expf(2.f * xn);
      float n = 1.f - __fdividef(2.f, en + 1.f);   // tanh(xn); en=inf -> 1, en=0 -> -1
      float hprev = h_s[j + ((j >> 5) << 2)];
      float hv = (1.f - z) * n + z * hprev;
      __hip_atomic_store(hbase + (size_t)t * 8192 + b * 512 + j, __float_as_uint(hv),
                         __ATOMIC_RELAXED, __HIP_MEMORY_SCOPE_AGENT);
      ys[((size_t)b * 64 + t) * 512 + j] = f2bf(hv);
      if (t == 63) hlast[b * 512 + j] = hv;
    }
    // no loop-end barrier: next step's phase-1 barrier provides the ordering
  }
}

// ---------- fused LSE combine + subtract: one block per row ----------
__global__ __launch_bounds__(256) void lse_sub_kernel(const float* __restrict__ partials,
                                                      float* __restrict__ out, int nnb) {
  __shared__ float sM[4], sS[4];
  int row = blockIdx.x;
  int tid = threadIdx.x;
  int lane = tid & 63, wv = tid >> 6;
  float M = -INFINITY, S = 0.f;
  if (tid < nnb) {
    const float* p = partials + ((size_t)row * nnb + tid) * 2;
    M = p[0]; S = p[1];
  }
  for (int d = 1; d < 64; d <<= 1) {
    float m2 = __shfl_xor(M, d), s2 = __shfl_xor(S, d);
    if (m2 > M) { float tt = M; M = m2; m2 = tt; tt = S; S = s2; s2 = tt; }
    if (s2 > 0.f) S += s2 * __expf(m2 - M);
  }
  if (lane == 0) { sM[wv] = M; sS[wv] = S; }
  __syncthreads();
  M = sM[0]; S = sS[0];
  for (int w = 1; w < 4; ++w) {
    float m2 = sM[w], s2 = sS[w];
    if (m2 > M) { float tt = M; M = m2; m2 = tt; tt = S; S = s2; s2 = tt; }
    if (s2 > 0.f) S += s2 * __expf(m2 - M);
  }
  float l = M + logf(S);
  float4* po = reinterpret_cast<float4*>(out + (size_t)row * 32000);
  for (int i = tid; i < 8000; i += 256) {
    float4 v = po[i];
    v.x -= l; v.y -= l; v.z -= l; v.w -= l;
    po[i] = v;
  }
}

extern "C" void kernel_launch(void* const* d_in, const int* in_sizes, int n_in,
                              void* d_out, int out_size, void* d_ws, size_t ws_size,
                              hipStream_t stream) {
  const int* tseq = (const int*)d_in[0];
  const float* thought = (const float*)d_in[1];
  const float* hidden = (const float*)d_in[2];
  const float* emb = (const float*)d_in[3];
  const float* W_ih = (const float*)d_in[4];
  const float* W_hh = (const float*)d_in[5];
  const float* b_ih = (const float*)d_in[6];
  const float* b_hh = (const float*)d_in[7];
  const float* W_out = (const float*)d_in[8];
  const float* b_out = (const float*)d_in[9];
  float* out = (float*)d_out;

  char* ws = (char*)d_ws;
  size_t off = 0;
  auto alloc = [&](size_t bytes) {
    void* p = ws + off;
    off = (off + bytes + 255) & ~(size_t)255;
    return p;
  };
  u16* wout_bf = (u16*)alloc((size_t)32000 * 512 * 2);
  u16* wih_bf  = (u16*)alloc((size_t)1536 * 1024 * 2);
  u16* x_bf    = (u16*)alloc((size_t)1024 * 1024 * 2);
  u16* ys_bf   = (u16*)alloc((size_t)1024 * 512 * 2);
  float* gi    = (float*)alloc((size_t)1024 * 1536 * 4);
  u32* hbase   = (u32*)alloc((size_t)64 * 16 * 512 * 4);
  float* partials = (float*)alloc((size_t)1024 * 250 * 2 * 4);
  (void)ws_size; (void)in_sizes; (void)n_in; (void)out_size;

  // 5 graph nodes total (was 9): pre, gemm1, gru, gemm2, lse_sub
  pre_kernel<<<3072, 256, 0, stream>>>(W_ih, wih_bf, tseq, emb, thought, x_bf, hbase);
  gemm_bt_kernel<false><<<96, 256, 0, stream>>>(x_bf, wih_bf, b_ih, gi,
                                                1024, 1536, 1024, nullptr, 0);
  // gru: 512 recurrence WGs + 256 converter WGs (W_out cvt hidden in latency shadow)
  gru_kernel<<<768, 256, 0, stream>>>(gi, W_hh, b_hh, hidden, hbase, ys_bf,
                                      out + 32768000, W_out, wout_bf);
  gemm_bt_kernel<true><<<2000, 256, 0, stream>>>(ys_bf, wout_bf, b_out, out,
                                                 1024, 32000, 512, partials, 250);
  lse_sub_kernel<<<1024, 256, 0, stream>>>(partials, out, 250);
}